// Round 19
// baseline (2165.543 us; speedup 1.0000x reference)
//
#include <hip/hip_runtime.h>
#include <hip/hip_bf16.h>
#include <math.h>

#define NPTS    16384
#define DIM     128
#define KSEL    16
#define TSEL    18      // per-scanner top list (16 + self + 1 margin)
#define THREADS 256
#define RPB     32      // rows per block
#define NSC     8       // scanners per row per block: 2 streams x 4 lane-grps
#define NC      (NSC * TSEL)   // 144 candidates per row per block
#define CSTRIDE 145            // padded per-row stride (u64 keys)

typedef float f32x4  __attribute__((ext_vector_type(4)));
typedef short bf16x8 __attribute__((ext_vector_type(8)));

__device__ __forceinline__ unsigned short f2b(float f) {
    __hip_bfloat16 h = __float2bfloat16(f);   // RTNE
    return *(unsigned short*)&h;
}

// BIT-EXACT numpy f32 pairwise-sum of x*x (AVX512 path) — validated R9.
__device__ __forceinline__ float np_sq_avx512(const float* __restrict__ x) {
    float s[16];
    #pragma unroll
    for (int L = 0; L < 16; ++L) {
        const float m0 = __fmul_rn(x[  0 + L], x[  0 + L]);
        const float m1 = __fmul_rn(x[ 16 + L], x[ 16 + L]);
        const float m2 = __fmul_rn(x[ 32 + L], x[ 32 + L]);
        const float m3 = __fmul_rn(x[ 48 + L], x[ 48 + L]);
        const float m4 = __fmul_rn(x[ 64 + L], x[ 64 + L]);
        const float m5 = __fmul_rn(x[ 80 + L], x[ 80 + L]);
        const float m6 = __fmul_rn(x[ 96 + L], x[ 96 + L]);
        const float m7 = __fmul_rn(x[112 + L], x[112 + L]);
        s[L] = __fadd_rn(
            __fadd_rn(__fadd_rn(m0, m1), __fadd_rn(m2, m3)),
            __fadd_rn(__fadd_rn(m4, m5), __fadd_rn(m6, m7)));
    }
    float u[8];
    #pragma unroll
    for (int i = 0; i < 8; ++i) u[i] = __fadd_rn(s[i], s[i + 8]);
    float v[4];
    #pragma unroll
    for (int i = 0; i < 4; ++i) v[i] = __fadd_rn(u[i], u[i + 4]);
    return __fadd_rn(__fadd_rn(v[0], v[2]), __fadd_rn(v[1], v[3]));
}

// scan-phase sq (capture key only)
__device__ __forceinline__ float scan_sq(const float* __restrict__ xp) {
    const float4* x4 = (const float4*)xp;
    float a0 = 0.f, a1 = 0.f, a2 = 0.f, a3 = 0.f;
    #pragma unroll
    for (int g = 0; g < 32; ++g) {
        const float4 b = x4[g];
        a0 += b.x * b.x; a1 += b.y * b.y;
        a2 += b.z * b.z; a3 += b.w * b.w;
    }
    return (a0 + a1) + (a2 + a3);
}

__global__ __launch_bounds__(256)
void sq_kernel(const float* __restrict__ X, float* __restrict__ sqws) {
    const int j = blockIdx.x * 256 + threadIdx.x;
    sqws[j] = 0.5f * scan_sq(X + (size_t)j * DIM);   // half-scale scan key
}

__global__ __launch_bounds__(256)
void cvt_kernel(const float* __restrict__ X, unsigned short* __restrict__ Xb) {
    const size_t i = ((size_t)blockIdx.x * 256 + threadIdx.x) * 8;
    const float4 v0 = *(const float4*)(X + i);
    const float4 v1 = *(const float4*)(X + i + 4);
    ushort4 o0, o1;
    o0.x = f2b(v0.x); o0.y = f2b(v0.y); o0.z = f2b(v0.z); o0.w = f2b(v0.w);
    o1.x = f2b(v1.x); o1.y = f2b(v1.y); o1.z = f2b(v1.z); o1.w = f2b(v1.w);
    *(ushort4*)(Xb + i) = o0;
    *(ushort4*)(Xb + i + 4) = o1;
}

// ---- split scan: block = (32 rows) x (column half). grid 1024 -> 4
// blocks/CU schedulable; launch_bounds(256,3) caps regs at 84 (reg law:
// 256/max(arg, block_waves_per_EU)); scan live set ~76, rescore ~50 -> no
// spill expected. Waves: 2 row-groups x 2 streams (2-way candidate L1
// sharing preserved). Numerics: scan=R14, rescore=R17 (both validated).
__global__ __launch_bounds__(THREADS, 3)
void scan_half(const float* __restrict__ X, const float* __restrict__ sqws,
               const unsigned short* __restrict__ Xb,
               unsigned long long* __restrict__ part) {
    __shared__ unsigned long long keys[RPB * CSTRIDE];   // 37120 B

    const int tid  = threadIdx.x;
    const int w    = tid >> 6;        // wave 0..3
    const int l    = tid & 63;
    const int lg   = l >> 4;          // lane-group 0..3
    const int l15  = l & 15;
    const int rg   = w >> 1;          // row-group 0..1
    const int ss   = w & 1;           // stream-in-half 0..1
    const int brow = blockIdx.x >> 1;
    const int half = blockIdx.x & 1;
    const int rloc = rg * 16 + l15;
    const int grow = brow * RPB + rloc;
    const int colbase = half * (NPTS / 2) + ss * (NPTS / 4);
    const int sid  = ss * 4 + lg;     // scanner 0..7

    // B fragments: NEGATED query row (R14 HAS_WS verbatim)
    bf16x8 nb[4];
    {
        const unsigned short* xr = Xb + (size_t)grow * DIM + lg * 8;
        #pragma unroll
        for (int m = 0; m < 4; ++m) {
            union { bf16x8 h; uint4 u; } t;
            t.h = *(const bf16x8*)(xr + m * 32);
            t.u.x ^= 0x80008000u; t.u.y ^= 0x80008000u;
            t.u.z ^= 0x80008000u; t.u.w ^= 0x80008000u;
            nb[m] = t.h;
        }
    }

    float bv[TSEL]; int bi[TSEL];
    #pragma unroll
    for (int k = 0; k < TSEL; ++k) { bv[k] = 3.0e38f; bi[k] = 0; }

    // MFMA scan over 256 tiles (R14 body verbatim; both rg waves of a
    // stream read the same candidates -> L1 sharing)
    const unsigned short* ap = Xb + (size_t)(colbase + l15) * DIM + lg * 8;
    #pragma unroll 1
    for (int t = 0; t < (NPTS / 4) / 16; ++t) {
        const int cb = colbase + t * 16;
        const bf16x8 a0 = *(const bf16x8*)(ap);
        const bf16x8 a1 = *(const bf16x8*)(ap + 32);
        const bf16x8 a2 = *(const bf16x8*)(ap + 64);
        const bf16x8 a3 = *(const bf16x8*)(ap + 96);
        ap += 16 * DIM;
        f32x4 acc = *(const f32x4*)&sqws[cb + lg * 4];
        acc = __builtin_amdgcn_mfma_f32_16x16x32_bf16(a0, nb[0], acc, 0, 0, 0);
        acc = __builtin_amdgcn_mfma_f32_16x16x32_bf16(a1, nb[1], acc, 0, 0, 0);
        acc = __builtin_amdgcn_mfma_f32_16x16x32_bf16(a2, nb[2], acc, 0, 0, 0);
        acc = __builtin_amdgcn_mfma_f32_16x16x32_bf16(a3, nb[3], acc, 0, 0, 0);
        #pragma unroll
        for (int r = 0; r < 4; ++r) {
            const float val = acc[r];
            if (val < bv[TSEL - 1]) {
                const int jg = cb + lg * 4 + r;
                #pragma unroll
                for (int k = TSEL - 1; k >= 1; --k) {
                    const bool m1 = val < bv[k - 1];
                    const bool m2 = val < bv[k];
                    bv[k] = m1 ? bv[k - 1] : (m2 ? val : bv[k]);
                    bi[k] = m1 ? bi[k - 1] : (m2 ? jg  : bi[k]);
                }
                if (val < bv[0]) { bv[0] = val; bi[0] = jg; }
            }
        }
    }

    // dump indices to own LDS slots (static unroll keeps bi in registers;
    // rule #20: the unroll-1 rescore below reads them back from LDS)
    #pragma unroll
    for (int k = 0; k < TSEL; ++k)
        keys[rloc * CSTRIDE + sid * TSEL + k] = (unsigned long long)bi[k];

    // rescore: bit-replica np f32 pipeline, x_i from global (R17 verbatim)
    const float* xip = X + (size_t)grow * DIM;
    const float4* xi4g = (const float4*)xip;
    const float sqi32 = np_sq_avx512(xip);

    #pragma unroll 1
    for (int k = 0; k < TSEL; ++k) {
        const int slot = rloc * CSTRIDE + sid * TSEL + k;
        const int j = (int)keys[slot];
        unsigned long long key;
        if (j == grow) {
            key = 0xFFFFFFFFFFFFFFFFULL;              // self: excluded
        } else {
            const float* xjp = X + (size_t)j * DIM;
            const float4* xj = (const float4*)xjp;
            const float sqj32 = np_sq_avx512(xjp);
            float cacc = 0.f;
            #pragma unroll
            for (int g = 0; g < 32; ++g) {
                const float4 a = xi4g[g], b = xj[g];
                cacc = __fmaf_rn(a.x, b.x, cacc);
                cacc = __fmaf_rn(a.y, b.y, cacc);
                cacc = __fmaf_rn(a.z, b.z, cacc);
                cacc = __fmaf_rn(a.w, b.w, cacc);
            }
            float d2c = __fsub_rn(__fadd_rn(sqi32, sqj32),
                                  __fmul_rn(2.0f, cacc));
            if (d2c < 0.0f) d2c = 0.0f;
            const float dist32 = sqrtf(d2c);          // f32 sqrt, correct rnd
            key = ((unsigned long long)__float_as_uint(dist32) << 32)
                  | (unsigned int)j;
        }
        keys[slot] = key;
    }
    __syncthreads();

    // per-row top-16 of this half's 144 keys -> sorted partial to ws
    if (tid < RPB) {
        const int base = tid * CSTRIDE;
        const int row = brow * RPB + tid;
        unsigned long long* po = part + ((size_t)row * 2 + half) * KSEL;
        for (int m = 0; m < KSEL; ++m) {
            unsigned long long best = 0xFFFFFFFFFFFFFFFFULL; int bc = 0;
            for (int c2 = 0; c2 < NC; ++c2) {
                const unsigned long long v = keys[base + c2];
                if (v < best) { best = v; bc = c2; }
            }
            po[m] = best;
            keys[base + bc] = 0xFFFFFFFFFFFFFFFFULL;
        }
    }
}

// final: merge two sorted-16 partial lists per row
__global__ __launch_bounds__(256)
void merge_kernel(const unsigned long long* __restrict__ part,
                  int* __restrict__ out) {
    const int row = blockIdx.x * 256 + threadIdx.x;
    const unsigned long long* A = part + (size_t)row * 32;
    const unsigned long long* B = A + 16;
    int ia = 0, ib = 0;
    #pragma unroll 1
    for (int m = 0; m < KSEL; ++m) {
        const unsigned long long va = (ia < 16) ? A[ia] : 0xFFFFFFFFFFFFFFFFULL;
        const unsigned long long vb = (ib < 16) ? B[ib] : 0xFFFFFFFFFFFFFFFFULL;
        const bool ta = va < vb;
        out[(size_t)row * KSEL + m] = (int)((ta ? va : vb) & 0xFFFFFFFFULL);
        ia += ta; ib += !ta;
    }
}

// ---- fallback monolith: R14 verbatim (proven 1458us, absmax 0) ----
template <bool HAS_WS>
__global__ __launch_bounds__(THREADS, 2)
void mono_kernel(const float* __restrict__ X, const float* __restrict__ sqws,
                 const unsigned short* __restrict__ Xb, int* __restrict__ out) {
    constexpr int SMEM = HAS_WS ? (RPB * CSTRIDE * 8) : (NPTS * 4);
    __shared__ __align__(16) char smem[SMEM];
    float* sqh = (float*)smem;
    unsigned long long* keys = (unsigned long long*)smem;
    const int tid = threadIdx.x;
    const int w = tid >> 6, l = tid & 63, lg = l >> 4, l15 = l & 15;
    const int rloc = (w >> 1) * 16 + l15;
    const int grow = blockIdx.x * RPB + rloc;
    const int colbase = (w & 1) * (NPTS / 2);
    const int s = (w & 1) * 4 + lg;
    if constexpr (!HAS_WS) {
        #pragma unroll 1
        for (int q = 0; q < NPTS / THREADS; ++q) {
            const int j = tid + THREADS * q;
            sqh[j] = 0.5f * scan_sq(X + (size_t)j * DIM);
        }
        __syncthreads();
    }
    bf16x8 nb[4];
    if constexpr (HAS_WS) {
        const unsigned short* xr = Xb + (size_t)grow * DIM + lg * 8;
        #pragma unroll
        for (int m = 0; m < 4; ++m) {
            union { bf16x8 h; uint4 u; } t;
            t.h = *(const bf16x8*)(xr + m * 32);
            t.u.x ^= 0x80008000u; t.u.y ^= 0x80008000u;
            t.u.z ^= 0x80008000u; t.u.w ^= 0x80008000u;
            nb[m] = t.h;
        }
    } else {
        const float* xr = X + (size_t)grow * DIM + lg * 8;
        #pragma unroll
        for (int m = 0; m < 4; ++m) {
            bf16x8 h;
            #pragma unroll
            for (int e = 0; e < 8; ++e) h[e] = (short)f2b(-xr[m * 32 + e]);
            nb[m] = h;
        }
    }
    float bv[TSEL]; int bi[TSEL];
    #pragma unroll
    for (int k = 0; k < TSEL; ++k) { bv[k] = 3.0e38f; bi[k] = 0; }
    const unsigned short* ap =
        HAS_WS ? Xb + (size_t)(colbase + l15) * DIM + lg * 8 : nullptr;
    const float* apf =
        HAS_WS ? nullptr : X + (size_t)(colbase + l15) * DIM + lg * 8;
    #pragma unroll 1
    for (int t = 0; t < (NPTS / 2) / 16; ++t) {
        const int cb = colbase + t * 16;
        bf16x8 a0, a1, a2, a3;
        if constexpr (HAS_WS) {
            a0 = *(const bf16x8*)(ap);
            a1 = *(const bf16x8*)(ap + 32);
            a2 = *(const bf16x8*)(ap + 64);
            a3 = *(const bf16x8*)(ap + 96);
            ap += 16 * DIM;
        } else {
            #pragma unroll
            for (int e = 0; e < 8; ++e) {
                a0[e] = (short)f2b(apf[e]);
                a1[e] = (short)f2b(apf[32 + e]);
                a2[e] = (short)f2b(apf[64 + e]);
                a3[e] = (short)f2b(apf[96 + e]);
            }
            apf += 16 * DIM;
        }
        f32x4 acc;
        if constexpr (HAS_WS) acc = *(const f32x4*)&sqws[cb + lg * 4];
        else                  acc = *(const f32x4*)&sqh [cb + lg * 4];
        acc = __builtin_amdgcn_mfma_f32_16x16x32_bf16(a0, nb[0], acc, 0, 0, 0);
        acc = __builtin_amdgcn_mfma_f32_16x16x32_bf16(a1, nb[1], acc, 0, 0, 0);
        acc = __builtin_amdgcn_mfma_f32_16x16x32_bf16(a2, nb[2], acc, 0, 0, 0);
        acc = __builtin_amdgcn_mfma_f32_16x16x32_bf16(a3, nb[3], acc, 0, 0, 0);
        #pragma unroll
        for (int r = 0; r < 4; ++r) {
            const float val = acc[r];
            if (val < bv[TSEL - 1]) {
                const int jg = cb + lg * 4 + r;
                #pragma unroll
                for (int k = TSEL - 1; k >= 1; --k) {
                    const bool m1 = val < bv[k - 1];
                    const bool m2 = val < bv[k];
                    bv[k] = m1 ? bv[k - 1] : (m2 ? val : bv[k]);
                    bi[k] = m1 ? bi[k - 1] : (m2 ? jg  : bi[k]);
                }
                if (val < bv[0]) { bv[0] = val; bi[0] = jg; }
            }
        }
    }
    __syncthreads();
    float4 xi4[32];
    {
        const float4* xr = (const float4*)(X + (size_t)grow * DIM);
        #pragma unroll
        for (int g = 0; g < 32; ++g) xi4[g] = xr[g];
    }
    const float sqi32 = np_sq_avx512(X + (size_t)grow * DIM);
    #pragma unroll
    for (int k = 0; k < TSEL; ++k) {
        const int j = bi[k];
        unsigned long long key;
        if (j == grow) {
            key = 0xFFFFFFFFFFFFFFFFULL;
        } else {
            const float* xjp = X + (size_t)j * DIM;
            const float4* xj = (const float4*)xjp;
            const float sqj32 = np_sq_avx512(xjp);
            float cacc = 0.f;
            #pragma unroll
            for (int g = 0; g < 32; ++g) {
                const float4 a = xi4[g], b = xj[g];
                cacc = __fmaf_rn(a.x, b.x, cacc);
                cacc = __fmaf_rn(a.y, b.y, cacc);
                cacc = __fmaf_rn(a.z, b.z, cacc);
                cacc = __fmaf_rn(a.w, b.w, cacc);
            }
            float d2c = __fsub_rn(__fadd_rn(sqi32, sqj32),
                                  __fmul_rn(2.0f, cacc));
            if (d2c < 0.0f) d2c = 0.0f;
            const float dist32 = sqrtf(d2c);
            key = ((unsigned long long)__float_as_uint(dist32) << 32)
                  | (unsigned int)j;
        }
        keys[rloc * CSTRIDE + s * TSEL + k] = key;
    }
    __syncthreads();
    if (tid < RPB) {
        const int base = tid * CSTRIDE;
        const int i = blockIdx.x * RPB + tid;
        for (int m = 0; m < KSEL; ++m) {
            unsigned long long best = 0xFFFFFFFFFFFFFFFFULL; int bc = 0;
            for (int c2 = 0; c2 < NC; ++c2) {
                const unsigned long long v = keys[base + c2];
                if (v < best) { best = v; bc = c2; }
            }
            out[(size_t)i * KSEL + m] = (int)(best & 0xFFFFFFFFULL);
            keys[base + bc] = 0xFFFFFFFFFFFFFFFFULL;
        }
    }
}

extern "C" void kernel_launch(void* const* d_in, const int* in_sizes, int n_in,
                              void* d_out, int out_size, void* d_ws, size_t ws_size,
                              hipStream_t stream) {
    (void)in_sizes; (void)n_in; (void)out_size;
    const float* X = (const float*)d_in[0];
    int* out = (int*)d_out;
    const size_t sqB = (size_t)NPTS * 4;                    // 64 KB
    const size_t xbB = (size_t)NPTS * DIM * 2;              // 4.19 MB
    const size_t partB = (size_t)NPTS * 2 * KSEL * 8;       // 4.19 MB
    float* sqws = (float*)d_ws;
    unsigned short* Xb = (unsigned short*)((char*)d_ws + sqB);
    unsigned long long* part = (unsigned long long*)((char*)d_ws + sqB + xbB);
    if (ws_size >= sqB + xbB + partB) {
        sq_kernel<<<dim3(NPTS / 256), dim3(256), 0, stream>>>(X, sqws);
        cvt_kernel<<<dim3(NPTS * DIM / 8 / 256), dim3(256), 0, stream>>>(X, Xb);
        scan_half<<<dim3((NPTS / RPB) * 2), dim3(THREADS), 0, stream>>>(X, sqws, Xb, part);
        merge_kernel<<<dim3(NPTS / 256), dim3(256), 0, stream>>>(part, out);
    } else if (ws_size >= sqB + xbB) {
        sq_kernel<<<dim3(NPTS / 256), dim3(256), 0, stream>>>(X, sqws);
        cvt_kernel<<<dim3(NPTS * DIM / 8 / 256), dim3(256), 0, stream>>>(X, Xb);
        mono_kernel<true><<<dim3(NPTS / RPB), dim3(THREADS), 0, stream>>>(X, sqws, Xb, out);
    } else {
        mono_kernel<false><<<dim3(NPTS / RPB), dim3(THREADS), 0, stream>>>(X, nullptr, nullptr, out);
    }
}

// Round 20
// 1999.502 us; speedup vs baseline: 1.0830x; 1.0830x over previous
//
#include <hip/hip_runtime.h>
#include <hip/hip_bf16.h>
#include <math.h>

#define NPTS    16384
#define DIM     128
#define KSEL    16
#define TSEL    18      // per-scanner top list (16 + self + 1 margin)
#define THREADS 256
#define RPB     32      // rows per block
#define NSC     8       // scanners per row per block: 2 streams x 4 lane-grps
#define CBUF    20      // collect slots per (row, scanner): >=18 + tie slack
#define CST2    (NSC * CBUF + 1)   // 161, per-row u64 stride
#define NC      (NSC * TSEL)       // 144 (mono path)
#define CSTRIDE 145                // mono path keys stride

typedef float f32x4  __attribute__((ext_vector_type(4)));
typedef short bf16x8 __attribute__((ext_vector_type(8)));

__device__ __forceinline__ unsigned short f2b(float f) {
    __hip_bfloat16 h = __float2bfloat16(f);   // RTNE
    return *(unsigned short*)&h;
}

// BIT-EXACT numpy f32 pairwise-sum of x*x (AVX512 path) — validated R9.
__device__ __forceinline__ float np_sq_avx512(const float* __restrict__ x) {
    float s[16];
    #pragma unroll
    for (int L = 0; L < 16; ++L) {
        const float m0 = __fmul_rn(x[  0 + L], x[  0 + L]);
        const float m1 = __fmul_rn(x[ 16 + L], x[ 16 + L]);
        const float m2 = __fmul_rn(x[ 32 + L], x[ 32 + L]);
        const float m3 = __fmul_rn(x[ 48 + L], x[ 48 + L]);
        const float m4 = __fmul_rn(x[ 64 + L], x[ 64 + L]);
        const float m5 = __fmul_rn(x[ 80 + L], x[ 80 + L]);
        const float m6 = __fmul_rn(x[ 96 + L], x[ 96 + L]);
        const float m7 = __fmul_rn(x[112 + L], x[112 + L]);
        s[L] = __fadd_rn(
            __fadd_rn(__fadd_rn(m0, m1), __fadd_rn(m2, m3)),
            __fadd_rn(__fadd_rn(m4, m5), __fadd_rn(m6, m7)));
    }
    float u[8];
    #pragma unroll
    for (int i = 0; i < 8; ++i) u[i] = __fadd_rn(s[i], s[i + 8]);
    float v[4];
    #pragma unroll
    for (int i = 0; i < 4; ++i) v[i] = __fadd_rn(u[i], u[i + 4]);
    return __fadd_rn(__fadd_rn(v[0], v[2]), __fadd_rn(v[1], v[3]));
}

// scan-phase sq (capture key only)
__device__ __forceinline__ float scan_sq(const float* __restrict__ xp) {
    const float4* x4 = (const float4*)xp;
    float a0 = 0.f, a1 = 0.f, a2 = 0.f, a3 = 0.f;
    #pragma unroll
    for (int g = 0; g < 32; ++g) {
        const float4 b = x4[g];
        a0 += b.x * b.x; a1 += b.y * b.y;
        a2 += b.z * b.z; a3 += b.w * b.w;
    }
    return (a0 + a1) + (a2 + a3);
}

__global__ __launch_bounds__(256)
void sq_kernel(const float* __restrict__ X, float* __restrict__ sqws) {
    const int j = blockIdx.x * 256 + threadIdx.x;
    sqws[j] = 0.5f * scan_sq(X + (size_t)j * DIM);   // half-scale scan key
}

__global__ __launch_bounds__(256)
void cvt_kernel(const float* __restrict__ X, unsigned short* __restrict__ Xb) {
    const size_t i = ((size_t)blockIdx.x * 256 + threadIdx.x) * 8;
    const float4 v0 = *(const float4*)(X + i);
    const float4 v1 = *(const float4*)(X + i + 4);
    ushort4 o0, o1;
    o0.x = f2b(v0.x); o0.y = f2b(v0.y); o0.z = f2b(v0.z); o0.w = f2b(v0.w);
    o1.x = f2b(v1.x); o1.y = f2b(v1.y); o1.z = f2b(v1.z); o1.w = f2b(v1.w);
    *(ushort4*)(Xb + i) = o0;
    *(ushort4*)(Xb + i + 4) = o1;
}

// ---- two-pass scan over a column half. (256,3) caps regs at 84; pass A
// live set ~64 (values-only top-18, no index list) -> no spill expected.
// Pass B re-runs the IDENTICAL MFMA stream (bit-identical accs) and collects
// indices with acc <= bv[17] into lane-private LDS slots (no atomics,
// deterministic). LDS 41.2 KB -> 3 blocks/CU.
__global__ __launch_bounds__(THREADS, 3)
void scan_half(const float* __restrict__ X, const float* __restrict__ sqws,
               const unsigned short* __restrict__ Xb,
               unsigned long long* __restrict__ part) {
    __shared__ unsigned long long cand[RPB * CST2];   // 41216 B

    const int tid  = threadIdx.x;
    const int w    = tid >> 6;        // wave 0..3
    const int l    = tid & 63;
    const int lg   = l >> 4;          // lane-group 0..3
    const int l15  = l & 15;
    const int rg   = w >> 1;          // row-group 0..1
    const int ss   = w & 1;           // stream-in-half 0..1
    const int brow = blockIdx.x >> 1;
    const int half = blockIdx.x & 1;
    const int rloc = rg * 16 + l15;
    const int grow = brow * RPB + rloc;
    const int colbase = half * (NPTS / 2) + ss * (NPTS / 4);
    const int sid  = ss * 4 + lg;     // scanner 0..7

    // B fragments: NEGATED query row (validated R13+)
    bf16x8 nb[4];
    {
        const unsigned short* xr = Xb + (size_t)grow * DIM + lg * 8;
        #pragma unroll
        for (int m = 0; m < 4; ++m) {
            union { bf16x8 h; uint4 u; } t;
            t.h = *(const bf16x8*)(xr + m * 32);
            t.u.x ^= 0x80008000u; t.u.y ^= 0x80008000u;
            t.u.z ^= 0x80008000u; t.u.w ^= 0x80008000u;
            nb[m] = t.h;
        }
    }

    // ---- pass A: values-only top-TSEL (threshold discovery) ----
    float bv[TSEL];
    #pragma unroll
    for (int k = 0; k < TSEL; ++k) bv[k] = 3.0e38f;

    {
        const unsigned short* ap = Xb + (size_t)(colbase + l15) * DIM + lg * 8;
        #pragma unroll 1
        for (int t = 0; t < (NPTS / 4) / 16; ++t) {
            const int cb = colbase + t * 16;
            const bf16x8 a0 = *(const bf16x8*)(ap);
            const bf16x8 a1 = *(const bf16x8*)(ap + 32);
            const bf16x8 a2 = *(const bf16x8*)(ap + 64);
            const bf16x8 a3 = *(const bf16x8*)(ap + 96);
            ap += 16 * DIM;
            f32x4 acc = *(const f32x4*)&sqws[cb + lg * 4];
            acc = __builtin_amdgcn_mfma_f32_16x16x32_bf16(a0, nb[0], acc, 0, 0, 0);
            acc = __builtin_amdgcn_mfma_f32_16x16x32_bf16(a1, nb[1], acc, 0, 0, 0);
            acc = __builtin_amdgcn_mfma_f32_16x16x32_bf16(a2, nb[2], acc, 0, 0, 0);
            acc = __builtin_amdgcn_mfma_f32_16x16x32_bf16(a3, nb[3], acc, 0, 0, 0);
            #pragma unroll
            for (int r = 0; r < 4; ++r) {
                const float val = acc[r];
                if (val < bv[TSEL - 1]) {
                    #pragma unroll
                    for (int k = TSEL - 1; k >= 1; --k) {
                        const bool m1 = val < bv[k - 1];
                        const bool m2 = val < bv[k];
                        bv[k] = m1 ? bv[k - 1] : (m2 ? val : bv[k]);
                    }
                    if (val < bv[0]) bv[0] = val;
                }
            }
        }
    }
    const float T = bv[TSEL - 1];   // 18th-smallest scan value of this stream

    // ---- init own slots, then pass B: collect indices (lane-local) ----
    #pragma unroll
    for (int c = 0; c < CBUF; ++c)
        cand[rloc * CST2 + sid * CBUF + c] = 0xFFFFFFFFFFFFFFFFULL;

    {
        int cnt = 0;
        const unsigned short* ap = Xb + (size_t)(colbase + l15) * DIM + lg * 8;
        #pragma unroll 1
        for (int t = 0; t < (NPTS / 4) / 16; ++t) {
            const int cb = colbase + t * 16;
            const bf16x8 a0 = *(const bf16x8*)(ap);
            const bf16x8 a1 = *(const bf16x8*)(ap + 32);
            const bf16x8 a2 = *(const bf16x8*)(ap + 64);
            const bf16x8 a3 = *(const bf16x8*)(ap + 96);
            ap += 16 * DIM;
            f32x4 acc = *(const f32x4*)&sqws[cb + lg * 4];
            acc = __builtin_amdgcn_mfma_f32_16x16x32_bf16(a0, nb[0], acc, 0, 0, 0);
            acc = __builtin_amdgcn_mfma_f32_16x16x32_bf16(a1, nb[1], acc, 0, 0, 0);
            acc = __builtin_amdgcn_mfma_f32_16x16x32_bf16(a2, nb[2], acc, 0, 0, 0);
            acc = __builtin_amdgcn_mfma_f32_16x16x32_bf16(a3, nb[3], acc, 0, 0, 0);
            #pragma unroll
            for (int r = 0; r < 4; ++r) {
                if (acc[r] <= T && cnt < CBUF) {
                    cand[rloc * CST2 + sid * CBUF + cnt] =
                        (unsigned long long)(unsigned int)(cb + lg * 4 + r);
                    ++cnt;
                }
            }
        }
    }

    // ---- rescore in place: bit-replica np f32 pipeline (validated R9/R17) ----
    const float* xip = X + (size_t)grow * DIM;
    const float4* xi4g = (const float4*)xip;
    const float sqi32 = np_sq_avx512(xip);

    #pragma unroll 1
    for (int k = 0; k < CBUF; ++k) {
        const int slot = rloc * CST2 + sid * CBUF + k;
        const unsigned long long j64 = cand[slot];
        if (j64 == 0xFFFFFFFFFFFFFFFFULL) continue;     // empty: key stays ~0
        const int j = (int)j64;
        if (j == grow) {
            cand[slot] = 0xFFFFFFFFFFFFFFFFULL;          // self: excluded
        } else {
            const float* xjp = X + (size_t)j * DIM;
            const float4* xj = (const float4*)xjp;
            const float sqj32 = np_sq_avx512(xjp);
            float cacc = 0.f;
            #pragma unroll
            for (int g = 0; g < 32; ++g) {
                const float4 a = xi4g[g], b = xj[g];
                cacc = __fmaf_rn(a.x, b.x, cacc);
                cacc = __fmaf_rn(a.y, b.y, cacc);
                cacc = __fmaf_rn(a.z, b.z, cacc);
                cacc = __fmaf_rn(a.w, b.w, cacc);
            }
            float d2c = __fsub_rn(__fadd_rn(sqi32, sqj32),
                                  __fmul_rn(2.0f, cacc));
            if (d2c < 0.0f) d2c = 0.0f;
            const float dist32 = sqrtf(d2c);             // f32 sqrt, correct
            cand[slot] = ((unsigned long long)__float_as_uint(dist32) << 32)
                         | (unsigned int)j;
        }
    }
    __syncthreads();

    // ---- per-row top-16 over this half's slots -> sorted partial to ws ----
    if (tid < RPB) {
        const int base = tid * CST2;
        const int row = brow * RPB + tid;
        unsigned long long* po = part + ((size_t)row * 2 + half) * KSEL;
        for (int m = 0; m < KSEL; ++m) {
            unsigned long long best = 0xFFFFFFFFFFFFFFFFULL; int bc = 0;
            for (int c2 = 0; c2 < NSC * CBUF; ++c2) {
                const unsigned long long v = cand[base + c2];
                if (v < best) { best = v; bc = c2; }
            }
            po[m] = best;
            cand[base + bc] = 0xFFFFFFFFFFFFFFFFULL;
        }
    }
}

// final: merge two sorted-16 partial lists per row (R19-proven)
__global__ __launch_bounds__(256)
void merge_kernel(const unsigned long long* __restrict__ part,
                  int* __restrict__ out) {
    const int row = blockIdx.x * 256 + threadIdx.x;
    const unsigned long long* A = part + (size_t)row * 32;
    const unsigned long long* B = A + 16;
    int ia = 0, ib = 0;
    #pragma unroll 1
    for (int m = 0; m < KSEL; ++m) {
        const unsigned long long va = (ia < 16) ? A[ia] : 0xFFFFFFFFFFFFFFFFULL;
        const unsigned long long vb = (ib < 16) ? B[ib] : 0xFFFFFFFFFFFFFFFFULL;
        const bool ta = va < vb;
        out[(size_t)row * KSEL + m] = (int)((ta ? va : vb) & 0xFFFFFFFFULL);
        ia += ta; ib += !ta;
    }
}

// ---- fallback monolith: R14 verbatim (proven 1458us, absmax 0) ----
template <bool HAS_WS>
__global__ __launch_bounds__(THREADS, 2)
void mono_kernel(const float* __restrict__ X, const float* __restrict__ sqws,
                 const unsigned short* __restrict__ Xb, int* __restrict__ out) {
    constexpr int SMEM = HAS_WS ? (RPB * CSTRIDE * 8) : (NPTS * 4);
    __shared__ __align__(16) char smem[SMEM];
    float* sqh = (float*)smem;
    unsigned long long* keys = (unsigned long long*)smem;
    const int tid = threadIdx.x;
    const int w = tid >> 6, l = tid & 63, lg = l >> 4, l15 = l & 15;
    const int rloc = (w >> 1) * 16 + l15;
    const int grow = blockIdx.x * RPB + rloc;
    const int colbase = (w & 1) * (NPTS / 2);
    const int s = (w & 1) * 4 + lg;
    if constexpr (!HAS_WS) {
        #pragma unroll 1
        for (int q = 0; q < NPTS / THREADS; ++q) {
            const int j = tid + THREADS * q;
            sqh[j] = 0.5f * scan_sq(X + (size_t)j * DIM);
        }
        __syncthreads();
    }
    bf16x8 nb[4];
    if constexpr (HAS_WS) {
        const unsigned short* xr = Xb + (size_t)grow * DIM + lg * 8;
        #pragma unroll
        for (int m = 0; m < 4; ++m) {
            union { bf16x8 h; uint4 u; } t;
            t.h = *(const bf16x8*)(xr + m * 32);
            t.u.x ^= 0x80008000u; t.u.y ^= 0x80008000u;
            t.u.z ^= 0x80008000u; t.u.w ^= 0x80008000u;
            nb[m] = t.h;
        }
    } else {
        const float* xr = X + (size_t)grow * DIM + lg * 8;
        #pragma unroll
        for (int m = 0; m < 4; ++m) {
            bf16x8 h;
            #pragma unroll
            for (int e = 0; e < 8; ++e) h[e] = (short)f2b(-xr[m * 32 + e]);
            nb[m] = h;
        }
    }
    float bv[TSEL]; int bi[TSEL];
    #pragma unroll
    for (int k = 0; k < TSEL; ++k) { bv[k] = 3.0e38f; bi[k] = 0; }
    const unsigned short* ap =
        HAS_WS ? Xb + (size_t)(colbase + l15) * DIM + lg * 8 : nullptr;
    const float* apf =
        HAS_WS ? nullptr : X + (size_t)(colbase + l15) * DIM + lg * 8;
    #pragma unroll 1
    for (int t = 0; t < (NPTS / 2) / 16; ++t) {
        const int cb = colbase + t * 16;
        bf16x8 a0, a1, a2, a3;
        if constexpr (HAS_WS) {
            a0 = *(const bf16x8*)(ap);
            a1 = *(const bf16x8*)(ap + 32);
            a2 = *(const bf16x8*)(ap + 64);
            a3 = *(const bf16x8*)(ap + 96);
            ap += 16 * DIM;
        } else {
            #pragma unroll
            for (int e = 0; e < 8; ++e) {
                a0[e] = (short)f2b(apf[e]);
                a1[e] = (short)f2b(apf[32 + e]);
                a2[e] = (short)f2b(apf[64 + e]);
                a3[e] = (short)f2b(apf[96 + e]);
            }
            apf += 16 * DIM;
        }
        f32x4 acc;
        if constexpr (HAS_WS) acc = *(const f32x4*)&sqws[cb + lg * 4];
        else                  acc = *(const f32x4*)&sqh [cb + lg * 4];
        acc = __builtin_amdgcn_mfma_f32_16x16x32_bf16(a0, nb[0], acc, 0, 0, 0);
        acc = __builtin_amdgcn_mfma_f32_16x16x32_bf16(a1, nb[1], acc, 0, 0, 0);
        acc = __builtin_amdgcn_mfma_f32_16x16x32_bf16(a2, nb[2], acc, 0, 0, 0);
        acc = __builtin_amdgcn_mfma_f32_16x16x32_bf16(a3, nb[3], acc, 0, 0, 0);
        #pragma unroll
        for (int r = 0; r < 4; ++r) {
            const float val = acc[r];
            if (val < bv[TSEL - 1]) {
                const int jg = cb + lg * 4 + r;
                #pragma unroll
                for (int k = TSEL - 1; k >= 1; --k) {
                    const bool m1 = val < bv[k - 1];
                    const bool m2 = val < bv[k];
                    bv[k] = m1 ? bv[k - 1] : (m2 ? val : bv[k]);
                    bi[k] = m1 ? bi[k - 1] : (m2 ? jg  : bi[k]);
                }
                if (val < bv[0]) { bv[0] = val; bi[0] = jg; }
            }
        }
    }
    __syncthreads();
    float4 xi4[32];
    {
        const float4* xr = (const float4*)(X + (size_t)grow * DIM);
        #pragma unroll
        for (int g = 0; g < 32; ++g) xi4[g] = xr[g];
    }
    const float sqi32 = np_sq_avx512(X + (size_t)grow * DIM);
    #pragma unroll
    for (int k = 0; k < TSEL; ++k) {
        const int j = bi[k];
        unsigned long long key;
        if (j == grow) {
            key = 0xFFFFFFFFFFFFFFFFULL;
        } else {
            const float* xjp = X + (size_t)j * DIM;
            const float4* xj = (const float4*)xjp;
            const float sqj32 = np_sq_avx512(xjp);
            float cacc = 0.f;
            #pragma unroll
            for (int g = 0; g < 32; ++g) {
                const float4 a = xi4[g], b = xj[g];
                cacc = __fmaf_rn(a.x, b.x, cacc);
                cacc = __fmaf_rn(a.y, b.y, cacc);
                cacc = __fmaf_rn(a.z, b.z, cacc);
                cacc = __fmaf_rn(a.w, b.w, cacc);
            }
            float d2c = __fsub_rn(__fadd_rn(sqi32, sqj32),
                                  __fmul_rn(2.0f, cacc));
            if (d2c < 0.0f) d2c = 0.0f;
            const float dist32 = sqrtf(d2c);
            key = ((unsigned long long)__float_as_uint(dist32) << 32)
                  | (unsigned int)j;
        }
        keys[rloc * CSTRIDE + s * TSEL + k] = key;
    }
    __syncthreads();
    if (tid < RPB) {
        const int base = tid * CSTRIDE;
        const int i = blockIdx.x * RPB + tid;
        for (int m = 0; m < KSEL; ++m) {
            unsigned long long best = 0xFFFFFFFFFFFFFFFFULL; int bc = 0;
            for (int c2 = 0; c2 < NC; ++c2) {
                const unsigned long long v = keys[base + c2];
                if (v < best) { best = v; bc = c2; }
            }
            out[(size_t)i * KSEL + m] = (int)(best & 0xFFFFFFFFULL);
            keys[base + bc] = 0xFFFFFFFFFFFFFFFFULL;
        }
    }
}

extern "C" void kernel_launch(void* const* d_in, const int* in_sizes, int n_in,
                              void* d_out, int out_size, void* d_ws, size_t ws_size,
                              hipStream_t stream) {
    (void)in_sizes; (void)n_in; (void)out_size;
    const float* X = (const float*)d_in[0];
    int* out = (int*)d_out;
    const size_t sqB = (size_t)NPTS * 4;                    // 64 KB
    const size_t xbB = (size_t)NPTS * DIM * 2;              // 4.19 MB
    const size_t partB = (size_t)NPTS * 2 * KSEL * 8;       // 4.19 MB
    float* sqws = (float*)d_ws;
    unsigned short* Xb = (unsigned short*)((char*)d_ws + sqB);
    unsigned long long* part = (unsigned long long*)((char*)d_ws + sqB + xbB);
    if (ws_size >= sqB + xbB + partB) {
        sq_kernel<<<dim3(NPTS / 256), dim3(256), 0, stream>>>(X, sqws);
        cvt_kernel<<<dim3(NPTS * DIM / 8 / 256), dim3(256), 0, stream>>>(X, Xb);
        scan_half<<<dim3((NPTS / RPB) * 2), dim3(THREADS), 0, stream>>>(X, sqws, Xb, part);
        merge_kernel<<<dim3(NPTS / 256), dim3(256), 0, stream>>>(part, out);
    } else if (ws_size >= sqB + xbB) {
        sq_kernel<<<dim3(NPTS / 256), dim3(256), 0, stream>>>(X, sqws);
        cvt_kernel<<<dim3(NPTS * DIM / 8 / 256), dim3(256), 0, stream>>>(X, Xb);
        mono_kernel<true><<<dim3(NPTS / RPB), dim3(THREADS), 0, stream>>>(X, sqws, Xb, out);
    } else {
        mono_kernel<false><<<dim3(NPTS / RPB), dim3(THREADS), 0, stream>>>(X, nullptr, nullptr, out);
    }
}

// Round 21
// 1425.150 us; speedup vs baseline: 1.5195x; 1.4030x over previous
//
#include <hip/hip_runtime.h>
#include <hip/hip_bf16.h>
#include <math.h>

#define NPTS    16384
#define DIM     128
#define KSEL    16
#define TSEL    18      // per-scanner sorted top list (16 + self + 1 margin)
#define NSC     8       // scanners per row = 2 col-half waves x 4 lane-groups
#define RPB     32      // rows per block (2 row-groups x 16)
#define THREADS 256
#define NT      ((NPTS / 2) / 16)  // 512 candidate tiles per wave
#define NC      (NSC * TSEL)       // 144 candidates per row
#define CSTRIDE 145                // padded per-row stride (u64 keys)
#define KEYS_BYTES (RPB * CSTRIDE * 8)   // 37120

typedef float f32x4  __attribute__((ext_vector_type(4)));
typedef short bf16x8 __attribute__((ext_vector_type(8)));

__device__ __forceinline__ unsigned short f2b(float f) {
    __hip_bfloat16 h = __float2bfloat16(f);   // RTNE
    return *(unsigned short*)&h;
}

// BIT-EXACT numpy f32 pairwise-sum of x*x (AVX512 path) — validated R9.
__device__ __forceinline__ float np_sq_avx512(const float* __restrict__ x) {
    float s[16];
    #pragma unroll
    for (int L = 0; L < 16; ++L) {
        const float m0 = __fmul_rn(x[  0 + L], x[  0 + L]);
        const float m1 = __fmul_rn(x[ 16 + L], x[ 16 + L]);
        const float m2 = __fmul_rn(x[ 32 + L], x[ 32 + L]);
        const float m3 = __fmul_rn(x[ 48 + L], x[ 48 + L]);
        const float m4 = __fmul_rn(x[ 64 + L], x[ 64 + L]);
        const float m5 = __fmul_rn(x[ 80 + L], x[ 80 + L]);
        const float m6 = __fmul_rn(x[ 96 + L], x[ 96 + L]);
        const float m7 = __fmul_rn(x[112 + L], x[112 + L]);
        s[L] = __fadd_rn(
            __fadd_rn(__fadd_rn(m0, m1), __fadd_rn(m2, m3)),
            __fadd_rn(__fadd_rn(m4, m5), __fadd_rn(m6, m7)));
    }
    float u[8];
    #pragma unroll
    for (int i = 0; i < 8; ++i) u[i] = __fadd_rn(s[i], s[i + 8]);
    float v[4];
    #pragma unroll
    for (int i = 0; i < 4; ++i) v[i] = __fadd_rn(u[i], u[i + 4]);
    return __fadd_rn(__fadd_rn(v[0], v[2]), __fadd_rn(v[1], v[3]));
}

// scan-phase sq (capture key only)
__device__ __forceinline__ float scan_sq(const float* __restrict__ xp) {
    const float4* x4 = (const float4*)xp;
    float a0 = 0.f, a1 = 0.f, a2 = 0.f, a3 = 0.f;
    #pragma unroll
    for (int g = 0; g < 32; ++g) {
        const float4 b = x4[g];
        a0 += b.x * b.x; a1 += b.y * b.y;
        a2 += b.z * b.z; a3 += b.w * b.w;
    }
    return (a0 + a1) + (a2 + a3);
}

__global__ __launch_bounds__(256)
void sq_kernel(const float* __restrict__ X, float* __restrict__ sqws) {
    const int j = blockIdx.x * 256 + threadIdx.x;
    sqws[j] = 0.5f * scan_sq(X + (size_t)j * DIM);   // half-scale scan key
}

__global__ __launch_bounds__(256)
void cvt_kernel(const float* __restrict__ X, unsigned short* __restrict__ Xb) {
    const size_t i = ((size_t)blockIdx.x * 256 + threadIdx.x) * 8;
    const float4 v0 = *(const float4*)(X + i);
    const float4 v1 = *(const float4*)(X + i + 4);
    ushort4 o0, o1;
    o0.x = f2b(v0.x); o0.y = f2b(v0.y); o0.z = f2b(v0.z); o0.w = f2b(v0.w);
    o1.x = f2b(v1.x); o1.y = f2b(v1.y); o1.z = f2b(v1.z); o1.w = f2b(v1.w);
    *(ushort4*)(Xb + i) = o0;
    *(ushort4*)(Xb + i + 4) = o1;
}

// launch_bounds(256,2): the ONLY spill-free regime (R10/R17/R18/R19/R20 all
// spilled under tighter caps). R14 structure + scan-loop ILP:
//  (a) manual next-tile prefetch (+16 VGPR, hides L2 latency one full iter)
//  (b) split MFMA accumulator chains (halves dependency depth; scan-key
//      reassociation only — capture margin absorbs it, rescore is exact)
template <bool HAS_WS>
__global__ __launch_bounds__(THREADS, 2)
void knn_kernel(const float* __restrict__ X, const float* __restrict__ sqws,
                const unsigned short* __restrict__ Xb, int* __restrict__ out) {
    // HAS_WS:  LDS = 37.1 KB keys only.
    // !HAS_WS: LDS = 64 KB sq table during scan, keys overlay after.
    constexpr int SMEM = HAS_WS ? KEYS_BYTES : (NPTS * 4);
    __shared__ __align__(16) char smem[SMEM];
    float* sqh = (float*)smem;
    unsigned long long* keys = (unsigned long long*)smem;

    const int tid  = threadIdx.x;
    const int w    = tid >> 6;        // wave 0..3
    const int l    = tid & 63;        // lane
    const int lg   = l >> 4;          // lane-group 0..3
    const int l15  = l & 15;
    const int rloc = (w >> 1) * 16 + l15;           // local row 0..31
    const int grow = blockIdx.x * RPB + rloc;       // global query row
    const int colbase = (w & 1) * (NPTS / 2);       // column half
    const int sid = (w & 1) * 4 + lg;               // scanner 0..7

    if constexpr (!HAS_WS) {
        // per-block sq table (one-time; L2-hot reads)
        #pragma unroll 1
        for (int q = 0; q < NPTS / THREADS; ++q) {
            const int j = tid + THREADS * q;
            sqh[j] = 0.5f * scan_sq(X + (size_t)j * DIM);
        }
        __syncthreads();
    }

    // ---- B fragments: NEGATED query row, k-slices m*32 + lg*8 .. +8 ----
    // A and B share the lane->k mapping, so any k-permutation error cancels;
    // only the HW-verified C/D layout matters.
    bf16x8 nb[4];
    if constexpr (HAS_WS) {
        const unsigned short* xr = Xb + (size_t)grow * DIM + lg * 8;
        #pragma unroll
        for (int m = 0; m < 4; ++m) {
            union { bf16x8 h; uint4 u; } t;
            t.h = *(const bf16x8*)(xr + m * 32);
            t.u.x ^= 0x80008000u; t.u.y ^= 0x80008000u;
            t.u.z ^= 0x80008000u; t.u.w ^= 0x80008000u;
            nb[m] = t.h;
        }
    } else {
        const float* xr = X + (size_t)grow * DIM + lg * 8;
        #pragma unroll
        for (int m = 0; m < 4; ++m) {
            bf16x8 h;
            #pragma unroll
            for (int e = 0; e < 8; ++e) h[e] = (short)f2b(-xr[m * 32 + e]);
            nb[m] = h;
        }
    }

    // sorted ascending top-TSEL (scan key = 0.5*sq_j - dot, fp32 acc)
    float bv[TSEL]; int bi[TSEL];
    #pragma unroll
    for (int k = 0; k < TSEL; ++k) { bv[k] = 3.0e38f; bi[k] = 0; }

    // ---- MFMA scan with software pipeline (prefetch t+1 over tile t) ----
    if constexpr (HAS_WS) {
        const unsigned short* ap =
            Xb + (size_t)(colbase + l15) * DIM + lg * 8;
        bf16x8 c0 = *(const bf16x8*)(ap);
        bf16x8 c1 = *(const bf16x8*)(ap + 32);
        bf16x8 c2 = *(const bf16x8*)(ap + 64);
        bf16x8 c3 = *(const bf16x8*)(ap + 96);

        #pragma unroll 1
        for (int t = 0; t < NT; ++t) {
            const int cb = colbase + t * 16;
            // prefetch next tile (clamped re-load of last tile at the tail)
            const unsigned short* apn = (t + 1 < NT) ? ap + 16 * DIM : ap;
            const bf16x8 n0 = *(const bf16x8*)(apn);
            const bf16x8 n1 = *(const bf16x8*)(apn + 32);
            const bf16x8 n2 = *(const bf16x8*)(apn + 64);
            const bf16x8 n3 = *(const bf16x8*)(apn + 96);

            // two independent MFMA chains (half the dependency depth)
            f32x4 acc1 = *(const f32x4*)&sqws[cb + lg * 4];
            f32x4 acc2 = {0.f, 0.f, 0.f, 0.f};
            acc1 = __builtin_amdgcn_mfma_f32_16x16x32_bf16(c0, nb[0], acc1, 0, 0, 0);
            acc2 = __builtin_amdgcn_mfma_f32_16x16x32_bf16(c2, nb[2], acc2, 0, 0, 0);
            acc1 = __builtin_amdgcn_mfma_f32_16x16x32_bf16(c1, nb[1], acc1, 0, 0, 0);
            acc2 = __builtin_amdgcn_mfma_f32_16x16x32_bf16(c3, nb[3], acc2, 0, 0, 0);

            #pragma unroll
            for (int r = 0; r < 4; ++r) {
                const float val = acc1[r] + acc2[r];
                if (val < bv[TSEL - 1]) {             // rare after warm-up
                    const int jg = cb + lg * 4 + r;
                    #pragma unroll
                    for (int k = TSEL - 1; k >= 1; --k) {
                        const bool m1 = val < bv[k - 1];
                        const bool m2 = val < bv[k];
                        bv[k] = m1 ? bv[k - 1] : (m2 ? val : bv[k]);
                        bi[k] = m1 ? bi[k - 1] : (m2 ? jg  : bi[k]);
                    }
                    if (val < bv[0]) { bv[0] = val; bi[0] = jg; }
                }
            }
            c0 = n0; c1 = n1; c2 = n2; c3 = n3;
            ap = apn;
        }
    } else {
        const float* apf = X + (size_t)(colbase + l15) * DIM + lg * 8;
        #pragma unroll 1
        for (int t = 0; t < NT; ++t) {
            const int cb = colbase + t * 16;
            bf16x8 a0, a1, a2, a3;
            #pragma unroll
            for (int e = 0; e < 8; ++e) {
                a0[e] = (short)f2b(apf[e]);
                a1[e] = (short)f2b(apf[32 + e]);
                a2[e] = (short)f2b(apf[64 + e]);
                a3[e] = (short)f2b(apf[96 + e]);
            }
            apf += 16 * DIM;
            f32x4 acc = *(const f32x4*)&sqh[cb + lg * 4];
            acc = __builtin_amdgcn_mfma_f32_16x16x32_bf16(a0, nb[0], acc, 0, 0, 0);
            acc = __builtin_amdgcn_mfma_f32_16x16x32_bf16(a1, nb[1], acc, 0, 0, 0);
            acc = __builtin_amdgcn_mfma_f32_16x16x32_bf16(a2, nb[2], acc, 0, 0, 0);
            acc = __builtin_amdgcn_mfma_f32_16x16x32_bf16(a3, nb[3], acc, 0, 0, 0);
            #pragma unroll
            for (int r = 0; r < 4; ++r) {
                const float val = acc[r];
                if (val < bv[TSEL - 1]) {
                    const int jg = cb + lg * 4 + r;
                    #pragma unroll
                    for (int k = TSEL - 1; k >= 1; --k) {
                        const bool m1 = val < bv[k - 1];
                        const bool m2 = val < bv[k];
                        bv[k] = m1 ? bv[k - 1] : (m2 ? val : bv[k]);
                        bi[k] = m1 ? bi[k - 1] : (m2 ? jg  : bi[k]);
                    }
                    if (val < bv[0]) { bv[0] = val; bi[0] = jg; }
                }
            }
        }
    }

    __syncthreads();   // (!HAS_WS: done reading sqh) keys overlay begins

    // ---- rescore: bit-replica of the np f32 pipeline (validated R9) ----
    // own row in fp32 registers (loaded after scan, R14-verbatim)
    float4 xi4[32];
    {
        const float4* xr = (const float4*)(X + (size_t)grow * DIM);
        #pragma unroll
        for (int g = 0; g < 32; ++g) xi4[g] = xr[g];
    }
    const float sqi32 = np_sq_avx512(X + (size_t)grow * DIM);

    #pragma unroll
    for (int k = 0; k < TSEL; ++k) {
        const int j = bi[k];                          // register (static idx)
        unsigned long long key;
        if (j == grow) {
            key = 0xFFFFFFFFFFFFFFFFULL;              // self: excluded
        } else {
            const float* xjp = X + (size_t)j * DIM;
            const float4* xj = (const float4*)xjp;
            const float sqj32 = np_sq_avx512(xjp);
            float cacc = 0.f;
            #pragma unroll
            for (int g = 0; g < 32; ++g) {
                const float4 a = xi4[g], b = xj[g];
                cacc = __fmaf_rn(a.x, b.x, cacc);
                cacc = __fmaf_rn(a.y, b.y, cacc);
                cacc = __fmaf_rn(a.z, b.z, cacc);
                cacc = __fmaf_rn(a.w, b.w, cacc);
            }
            float d2c = __fsub_rn(__fadd_rn(sqi32, sqj32),
                                  __fmul_rn(2.0f, cacc));
            if (d2c < 0.0f) d2c = 0.0f;
            const float dist32 = sqrtf(d2c);          // f32 sqrt, correct rnd
            key = ((unsigned long long)__float_as_uint(dist32) << 32)
                  | (unsigned int)j;
        }
        keys[rloc * CSTRIDE + sid * TSEL + k] = key;
    }
    __syncthreads();

    // ---- per-row top-16 by packed key (serial, R14-verbatim) ----
    if (tid < RPB) {
        const int base = tid * CSTRIDE;
        const int i = blockIdx.x * RPB + tid;
        for (int m = 0; m < KSEL; ++m) {
            unsigned long long best = 0xFFFFFFFFFFFFFFFFULL; int bc = 0;
            for (int c2 = 0; c2 < NC; ++c2) {
                const unsigned long long v = keys[base + c2];
                if (v < best) { best = v; bc = c2; }
            }
            out[(size_t)i * KSEL + m] = (int)(best & 0xFFFFFFFFULL);
            keys[base + bc] = 0xFFFFFFFFFFFFFFFFULL;  // remove picked
        }
    }
}

extern "C" void kernel_launch(void* const* d_in, const int* in_sizes, int n_in,
                              void* d_out, int out_size, void* d_ws, size_t ws_size,
                              hipStream_t stream) {
    (void)in_sizes; (void)n_in; (void)out_size;
    const float* X = (const float*)d_in[0];
    int* out = (int*)d_out;
    const size_t WS_NEED = (size_t)NPTS * 4 + (size_t)NPTS * DIM * 2;  // 4.26MB
    if (ws_size >= WS_NEED) {   // proven available R13-R20
        float* sqws = (float*)d_ws;
        unsigned short* Xb = (unsigned short*)((char*)d_ws + (size_t)NPTS * 4);
        sq_kernel<<<dim3(NPTS / 256), dim3(256), 0, stream>>>(X, sqws);
        cvt_kernel<<<dim3(NPTS * DIM / 8 / 256), dim3(256), 0, stream>>>(X, Xb);
        knn_kernel<true><<<dim3(NPTS / RPB), dim3(THREADS), 0, stream>>>(X, sqws, Xb, out);
    } else {
        knn_kernel<false><<<dim3(NPTS / RPB), dim3(THREADS), 0, stream>>>(X, nullptr, nullptr, out);
    }
}

// Round 22
// 1411.187 us; speedup vs baseline: 1.5346x; 1.0099x over previous
//
#include <hip/hip_runtime.h>
#include <hip/hip_bf16.h>
#include <math.h>

#define NPTS    16384
#define DIM     128
#define KSEL    16
#define TSEL    18      // per-scanner top list (16 + self + 1 margin)
#define NSC     8       // scanners per row = 2 col-half waves x 4 lane-groups
#define RPB     32      // rows per block (2 row-groups x 16)
#define THREADS 256
#define NT      ((NPTS / 2) / 16)  // 512 candidate tiles per wave
#define CBUF    20      // collect slots per (row, scanner): 18 + tie slack
#define CST2    (NSC * CBUF + 1)   // 161 -> 41216 B LDS
#define NC      (NSC * TSEL)       // 144 (fallback path)
#define CSTRIDE 145                // fallback keys stride

typedef float f32x4  __attribute__((ext_vector_type(4)));
typedef short bf16x8 __attribute__((ext_vector_type(8)));

__device__ __forceinline__ unsigned short f2b(float f) {
    __hip_bfloat16 h = __float2bfloat16(f);   // RTNE
    return *(unsigned short*)&h;
}

// BIT-EXACT numpy f32 pairwise-sum of x*x (AVX512 path) — validated R9.
__device__ __forceinline__ float np_sq_avx512(const float* __restrict__ x) {
    float s[16];
    #pragma unroll
    for (int L = 0; L < 16; ++L) {
        const float m0 = __fmul_rn(x[  0 + L], x[  0 + L]);
        const float m1 = __fmul_rn(x[ 16 + L], x[ 16 + L]);
        const float m2 = __fmul_rn(x[ 32 + L], x[ 32 + L]);
        const float m3 = __fmul_rn(x[ 48 + L], x[ 48 + L]);
        const float m4 = __fmul_rn(x[ 64 + L], x[ 64 + L]);
        const float m5 = __fmul_rn(x[ 80 + L], x[ 80 + L]);
        const float m6 = __fmul_rn(x[ 96 + L], x[ 96 + L]);
        const float m7 = __fmul_rn(x[112 + L], x[112 + L]);
        s[L] = __fadd_rn(
            __fadd_rn(__fadd_rn(m0, m1), __fadd_rn(m2, m3)),
            __fadd_rn(__fadd_rn(m4, m5), __fadd_rn(m6, m7)));
    }
    float u[8];
    #pragma unroll
    for (int i = 0; i < 8; ++i) u[i] = __fadd_rn(s[i], s[i + 8]);
    float v[4];
    #pragma unroll
    for (int i = 0; i < 4; ++i) v[i] = __fadd_rn(u[i], u[i + 4]);
    return __fadd_rn(__fadd_rn(v[0], v[2]), __fadd_rn(v[1], v[3]));
}

// scan-phase sq (capture key only)
__device__ __forceinline__ float scan_sq(const float* __restrict__ xp) {
    const float4* x4 = (const float4*)xp;
    float a0 = 0.f, a1 = 0.f, a2 = 0.f, a3 = 0.f;
    #pragma unroll
    for (int g = 0; g < 32; ++g) {
        const float4 b = x4[g];
        a0 += b.x * b.x; a1 += b.y * b.y;
        a2 += b.z * b.z; a3 += b.w * b.w;
    }
    return (a0 + a1) + (a2 + a3);
}

__global__ __launch_bounds__(256)
void sq_kernel(const float* __restrict__ X, float* __restrict__ sqws) {
    const int j = blockIdx.x * 256 + threadIdx.x;
    sqws[j] = 0.5f * scan_sq(X + (size_t)j * DIM);   // half-scale scan key
}

__global__ __launch_bounds__(256)
void cvt_kernel(const float* __restrict__ X, unsigned short* __restrict__ Xb) {
    const size_t i = ((size_t)blockIdx.x * 256 + threadIdx.x) * 8;
    const float4 v0 = *(const float4*)(X + i);
    const float4 v1 = *(const float4*)(X + i + 4);
    ushort4 o0, o1;
    o0.x = f2b(v0.x); o0.y = f2b(v0.y); o0.z = f2b(v0.z); o0.w = f2b(v0.w);
    o1.x = f2b(v1.x); o1.y = f2b(v1.y); o1.z = f2b(v1.z); o1.w = f2b(v1.w);
    *(ushort4*)(Xb + i) = o0;
    *(ushort4*)(Xb + i + 4) = o1;
}

// Two-pass selection at the proven spill-free (256,2)/128-reg point:
//   pass A: values-only top-18 (cheap ~55-inst shift, no index list)
//   pass B: re-run the BIT-IDENTICAL MFMA stream, collect idx with
//           val <= T into lane-private LDS slots (no shifts)
// Two-pass semantics validated R20 (absmax 0); here without the reg spill.
__global__ __launch_bounds__(THREADS, 2)
void knn_twopass(const float* __restrict__ X, const float* __restrict__ sqws,
                 const unsigned short* __restrict__ Xb, int* __restrict__ out) {
    __shared__ unsigned long long cand[RPB * CST2];   // 41216 B

    const int tid  = threadIdx.x;
    const int w    = tid >> 6;        // wave 0..3
    const int l    = tid & 63;        // lane
    const int lg   = l >> 4;          // lane-group 0..3
    const int l15  = l & 15;
    const int rloc = (w >> 1) * 16 + l15;           // local row 0..31
    const int grow = blockIdx.x * RPB + rloc;       // global query row
    const int colbase = (w & 1) * (NPTS / 2);       // column half
    const int sid = (w & 1) * 4 + lg;               // scanner 0..7

    // ---- B fragments: NEGATED query row (validated R13+) ----
    bf16x8 nb[4];
    {
        const unsigned short* xr = Xb + (size_t)grow * DIM + lg * 8;
        #pragma unroll
        for (int m = 0; m < 4; ++m) {
            union { bf16x8 h; uint4 u; } t;
            t.h = *(const bf16x8*)(xr + m * 32);
            t.u.x ^= 0x80008000u; t.u.y ^= 0x80008000u;
            t.u.z ^= 0x80008000u; t.u.w ^= 0x80008000u;
            nb[m] = t.h;
        }
    }

    // ---- pass A: values-only top-TSEL with prefetch + split chains (R21) --
    float bv[TSEL];
    #pragma unroll
    for (int k = 0; k < TSEL; ++k) bv[k] = 3.0e38f;
    {
        const unsigned short* ap = Xb + (size_t)(colbase + l15) * DIM + lg * 8;
        bf16x8 c0 = *(const bf16x8*)(ap);
        bf16x8 c1 = *(const bf16x8*)(ap + 32);
        bf16x8 c2 = *(const bf16x8*)(ap + 64);
        bf16x8 c3 = *(const bf16x8*)(ap + 96);
        #pragma unroll 1
        for (int t = 0; t < NT; ++t) {
            const int cb = colbase + t * 16;
            const unsigned short* apn = (t + 1 < NT) ? ap + 16 * DIM : ap;
            const bf16x8 n0 = *(const bf16x8*)(apn);
            const bf16x8 n1 = *(const bf16x8*)(apn + 32);
            const bf16x8 n2 = *(const bf16x8*)(apn + 64);
            const bf16x8 n3 = *(const bf16x8*)(apn + 96);

            f32x4 acc1 = *(const f32x4*)&sqws[cb + lg * 4];
            f32x4 acc2 = {0.f, 0.f, 0.f, 0.f};
            acc1 = __builtin_amdgcn_mfma_f32_16x16x32_bf16(c0, nb[0], acc1, 0, 0, 0);
            acc2 = __builtin_amdgcn_mfma_f32_16x16x32_bf16(c2, nb[2], acc2, 0, 0, 0);
            acc1 = __builtin_amdgcn_mfma_f32_16x16x32_bf16(c1, nb[1], acc1, 0, 0, 0);
            acc2 = __builtin_amdgcn_mfma_f32_16x16x32_bf16(c3, nb[3], acc2, 0, 0, 0);

            #pragma unroll
            for (int r = 0; r < 4; ++r) {
                const float val = acc1[r] + acc2[r];
                if (val < bv[TSEL - 1]) {
                    #pragma unroll
                    for (int k = TSEL - 1; k >= 1; --k) {
                        const bool m1 = val < bv[k - 1];
                        const bool m2 = val < bv[k];
                        bv[k] = m1 ? bv[k - 1] : (m2 ? val : bv[k]);
                    }
                    if (val < bv[0]) bv[0] = val;
                }
            }
            c0 = n0; c1 = n1; c2 = n2; c3 = n3;
            ap = apn;
        }
    }
    const float T = bv[TSEL - 1];   // exact 18th-smallest of this stream

    // ---- init own slots, pass B: collect indices (bit-identical accs) ----
    #pragma unroll
    for (int c = 0; c < CBUF; ++c)
        cand[rloc * CST2 + sid * CBUF + c] = 0xFFFFFFFFFFFFFFFFULL;
    {
        int cnt = 0;
        const unsigned short* ap = Xb + (size_t)(colbase + l15) * DIM + lg * 8;
        #pragma unroll 1
        for (int t = 0; t < NT; ++t) {
            const int cb = colbase + t * 16;
            const bf16x8 a0 = *(const bf16x8*)(ap);
            const bf16x8 a1 = *(const bf16x8*)(ap + 32);
            const bf16x8 a2 = *(const bf16x8*)(ap + 64);
            const bf16x8 a3 = *(const bf16x8*)(ap + 96);
            ap += 16 * DIM;
            f32x4 acc1 = *(const f32x4*)&sqws[cb + lg * 4];
            f32x4 acc2 = {0.f, 0.f, 0.f, 0.f};
            acc1 = __builtin_amdgcn_mfma_f32_16x16x32_bf16(a0, nb[0], acc1, 0, 0, 0);
            acc2 = __builtin_amdgcn_mfma_f32_16x16x32_bf16(a2, nb[2], acc2, 0, 0, 0);
            acc1 = __builtin_amdgcn_mfma_f32_16x16x32_bf16(a1, nb[1], acc1, 0, 0, 0);
            acc2 = __builtin_amdgcn_mfma_f32_16x16x32_bf16(a3, nb[3], acc2, 0, 0, 0);
            #pragma unroll
            for (int r = 0; r < 4; ++r) {
                const float val = acc1[r] + acc2[r];   // same ops as pass A
                if (val <= T && cnt < CBUF) {
                    cand[rloc * CST2 + sid * CBUF + cnt] =
                        (unsigned long long)(unsigned int)(cb + lg * 4 + r);
                    ++cnt;
                }
            }
        }
    }

    // ---- rescore in place: bit-replica np f32 pipeline (validated R9) ----
    float4 xi4[32];
    {
        const float4* xr = (const float4*)(X + (size_t)grow * DIM);
        #pragma unroll
        for (int g = 0; g < 32; ++g) xi4[g] = xr[g];
    }
    const float sqi32 = np_sq_avx512(X + (size_t)grow * DIM);

    #pragma unroll 1
    for (int k = 0; k < CBUF; ++k) {
        const int slot = rloc * CST2 + sid * CBUF + k;
        const unsigned long long j64 = cand[slot];
        if (j64 == 0xFFFFFFFFFFFFFFFFULL) continue;   // empty slot
        const int j = (int)j64;
        if (j == grow) {
            cand[slot] = 0xFFFFFFFFFFFFFFFFULL;        // self: excluded
        } else {
            const float* xjp = X + (size_t)j * DIM;
            const float4* xj = (const float4*)xjp;
            const float sqj32 = np_sq_avx512(xjp);
            float cacc = 0.f;
            #pragma unroll
            for (int g = 0; g < 32; ++g) {
                const float4 a = xi4[g], b = xj[g];
                cacc = __fmaf_rn(a.x, b.x, cacc);
                cacc = __fmaf_rn(a.y, b.y, cacc);
                cacc = __fmaf_rn(a.z, b.z, cacc);
                cacc = __fmaf_rn(a.w, b.w, cacc);
            }
            float d2c = __fsub_rn(__fadd_rn(sqi32, sqj32),
                                  __fmul_rn(2.0f, cacc));
            if (d2c < 0.0f) d2c = 0.0f;
            const float dist32 = sqrtf(d2c);           // f32 sqrt, correct rnd
            cand[slot] = ((unsigned long long)__float_as_uint(dist32) << 32)
                         | (unsigned int)j;
        }
    }
    __syncthreads();

    // ---- per-row top-16 over 160 slots (serial, R20-validated) ----
    if (tid < RPB) {
        const int base = tid * CST2;
        const int i = blockIdx.x * RPB + tid;
        for (int m = 0; m < KSEL; ++m) {
            unsigned long long best = 0xFFFFFFFFFFFFFFFFULL; int bc = 0;
            for (int c2 = 0; c2 < NSC * CBUF; ++c2) {
                const unsigned long long v = cand[base + c2];
                if (v < best) { best = v; bc = c2; }
            }
            out[(size_t)i * KSEL + m] = (int)(best & 0xFFFFFFFFULL);
            cand[base + bc] = 0xFFFFFFFFFFFFFFFFULL;  // remove picked
        }
    }
}

// ---- fallback monolith (R14 verbatim, proven; used only without ws) ----
__global__ __launch_bounds__(THREADS, 2)
void knn_mono(const float* __restrict__ X, int* __restrict__ out) {
    __shared__ __align__(16) char smem[NPTS * 4];
    float* sqh = (float*)smem;
    unsigned long long* keys = (unsigned long long*)smem;
    const int tid = threadIdx.x;
    const int w = tid >> 6, l = tid & 63, lg = l >> 4, l15 = l & 15;
    const int rloc = (w >> 1) * 16 + l15;
    const int grow = blockIdx.x * RPB + rloc;
    const int colbase = (w & 1) * (NPTS / 2);
    const int s = (w & 1) * 4 + lg;
    #pragma unroll 1
    for (int q = 0; q < NPTS / THREADS; ++q) {
        const int j = tid + THREADS * q;
        sqh[j] = 0.5f * scan_sq(X + (size_t)j * DIM);
    }
    __syncthreads();
    bf16x8 nb[4];
    {
        const float* xr = X + (size_t)grow * DIM + lg * 8;
        #pragma unroll
        for (int m = 0; m < 4; ++m) {
            bf16x8 h;
            #pragma unroll
            for (int e = 0; e < 8; ++e) h[e] = (short)f2b(-xr[m * 32 + e]);
            nb[m] = h;
        }
    }
    float bv[TSEL]; int bi[TSEL];
    #pragma unroll
    for (int k = 0; k < TSEL; ++k) { bv[k] = 3.0e38f; bi[k] = 0; }
    const float* apf = X + (size_t)(colbase + l15) * DIM + lg * 8;
    #pragma unroll 1
    for (int t = 0; t < NT; ++t) {
        const int cb = colbase + t * 16;
        bf16x8 a0, a1, a2, a3;
        #pragma unroll
        for (int e = 0; e < 8; ++e) {
            a0[e] = (short)f2b(apf[e]);
            a1[e] = (short)f2b(apf[32 + e]);
            a2[e] = (short)f2b(apf[64 + e]);
            a3[e] = (short)f2b(apf[96 + e]);
        }
        apf += 16 * DIM;
        f32x4 acc = *(const f32x4*)&sqh[cb + lg * 4];
        acc = __builtin_amdgcn_mfma_f32_16x16x32_bf16(a0, nb[0], acc, 0, 0, 0);
        acc = __builtin_amdgcn_mfma_f32_16x16x32_bf16(a1, nb[1], acc, 0, 0, 0);
        acc = __builtin_amdgcn_mfma_f32_16x16x32_bf16(a2, nb[2], acc, 0, 0, 0);
        acc = __builtin_amdgcn_mfma_f32_16x16x32_bf16(a3, nb[3], acc, 0, 0, 0);
        #pragma unroll
        for (int r = 0; r < 4; ++r) {
            const float val = acc[r];
            if (val < bv[TSEL - 1]) {
                const int jg = cb + lg * 4 + r;
                #pragma unroll
                for (int k = TSEL - 1; k >= 1; --k) {
                    const bool m1 = val < bv[k - 1];
                    const bool m2 = val < bv[k];
                    bv[k] = m1 ? bv[k - 1] : (m2 ? val : bv[k]);
                    bi[k] = m1 ? bi[k - 1] : (m2 ? jg  : bi[k]);
                }
                if (val < bv[0]) { bv[0] = val; bi[0] = jg; }
            }
        }
    }
    __syncthreads();
    float4 xi4[32];
    {
        const float4* xr = (const float4*)(X + (size_t)grow * DIM);
        #pragma unroll
        for (int g = 0; g < 32; ++g) xi4[g] = xr[g];
    }
    const float sqi32 = np_sq_avx512(X + (size_t)grow * DIM);
    #pragma unroll
    for (int k = 0; k < TSEL; ++k) {
        const int j = bi[k];
        unsigned long long key;
        if (j == grow) {
            key = 0xFFFFFFFFFFFFFFFFULL;
        } else {
            const float* xjp = X + (size_t)j * DIM;
            const float4* xj = (const float4*)xjp;
            const float sqj32 = np_sq_avx512(xjp);
            float cacc = 0.f;
            #pragma unroll
            for (int g = 0; g < 32; ++g) {
                const float4 a = xi4[g], b = xj[g];
                cacc = __fmaf_rn(a.x, b.x, cacc);
                cacc = __fmaf_rn(a.y, b.y, cacc);
                cacc = __fmaf_rn(a.z, b.z, cacc);
                cacc = __fmaf_rn(a.w, b.w, cacc);
            }
            float d2c = __fsub_rn(__fadd_rn(sqi32, sqj32),
                                  __fmul_rn(2.0f, cacc));
            if (d2c < 0.0f) d2c = 0.0f;
            const float dist32 = sqrtf(d2c);
            key = ((unsigned long long)__float_as_uint(dist32) << 32)
                  | (unsigned int)j;
        }
        keys[rloc * CSTRIDE + s * TSEL + k] = key;
    }
    __syncthreads();
    if (tid < RPB) {
        const int base = tid * CSTRIDE;
        const int i = blockIdx.x * RPB + tid;
        for (int m = 0; m < KSEL; ++m) {
            unsigned long long best = 0xFFFFFFFFFFFFFFFFULL; int bc = 0;
            for (int c2 = 0; c2 < NC; ++c2) {
                const unsigned long long v = keys[base + c2];
                if (v < best) { best = v; bc = c2; }
            }
            out[(size_t)i * KSEL + m] = (int)(best & 0xFFFFFFFFULL);
            keys[base + bc] = 0xFFFFFFFFFFFFFFFFULL;
        }
    }
}

extern "C" void kernel_launch(void* const* d_in, const int* in_sizes, int n_in,
                              void* d_out, int out_size, void* d_ws, size_t ws_size,
                              hipStream_t stream) {
    (void)in_sizes; (void)n_in; (void)out_size;
    const float* X = (const float*)d_in[0];
    int* out = (int*)d_out;
    const size_t WS_NEED = (size_t)NPTS * 4 + (size_t)NPTS * DIM * 2;  // 4.26MB
    if (ws_size >= WS_NEED) {   // proven available R13-R21
        float* sqws = (float*)d_ws;
        unsigned short* Xb = (unsigned short*)((char*)d_ws + (size_t)NPTS * 4);
        sq_kernel<<<dim3(NPTS / 256), dim3(256), 0, stream>>>(X, sqws);
        cvt_kernel<<<dim3(NPTS * DIM / 8 / 256), dim3(256), 0, stream>>>(X, Xb);
        knn_twopass<<<dim3(NPTS / RPB), dim3(THREADS), 0, stream>>>(X, sqws, Xb, out);
    } else {
        knn_mono<<<dim3(NPTS / RPB), dim3(THREADS), 0, stream>>>(X, out);
    }
}

// Round 23
// 1372.154 us; speedup vs baseline: 1.5782x; 1.0284x over previous
//
#include <hip/hip_runtime.h>
#include <hip/hip_bf16.h>
#include <math.h>

#define NPTS    16384
#define DIM     128
#define KSEL    16
#define TSEL    18      // per-scanner top list (16 + self + 1 margin)
#define NSC     8       // scanners per row = 2 col-half waves x 4 lane-groups
#define RPB     32      // rows per block (2 row-groups x 16)
#define THREADS 256
#define NT      ((NPTS / 2) / 16)  // 512 candidate tiles per wave
#define CBUF    20      // collect slots per (row, scanner): 18 + tie slack
#define CST2    (NSC * CBUF + 1)   // 161 -> 41216 B LDS
#define NC      (NSC * TSEL)       // 144 (fallback path)
#define CSTRIDE 145                // fallback keys stride

typedef float f32x4  __attribute__((ext_vector_type(4)));
typedef short bf16x8 __attribute__((ext_vector_type(8)));

__device__ __forceinline__ unsigned short f2b(float f) {
    __hip_bfloat16 h = __float2bfloat16(f);   // RTNE
    return *(unsigned short*)&h;
}

// branchless sorted-insert level: new bv[k] = k-th smallest after inserting
// val (median identity; bv sorted ascending so med3(bv[k-1],bv[k],val) ==
// min(bv[k], max(bv[k-1], val)) -- clang fuses to v_med3_f32)
#define MED3_LADDER(bv, val)                                   \
    do {                                                       \
        _Pragma("unroll")                                      \
        for (int k = TSEL - 1; k >= 1; --k)                    \
            bv[k] = fminf(bv[k], fmaxf(bv[k - 1], (val)));     \
        bv[0] = fminf(bv[0], (val));                           \
    } while (0)

// BIT-EXACT numpy f32 pairwise-sum of x*x (AVX512 path) — validated R9.
__device__ __forceinline__ float np_sq_avx512(const float* __restrict__ x) {
    float s[16];
    #pragma unroll
    for (int L = 0; L < 16; ++L) {
        const float m0 = __fmul_rn(x[  0 + L], x[  0 + L]);
        const float m1 = __fmul_rn(x[ 16 + L], x[ 16 + L]);
        const float m2 = __fmul_rn(x[ 32 + L], x[ 32 + L]);
        const float m3 = __fmul_rn(x[ 48 + L], x[ 48 + L]);
        const float m4 = __fmul_rn(x[ 64 + L], x[ 64 + L]);
        const float m5 = __fmul_rn(x[ 80 + L], x[ 80 + L]);
        const float m6 = __fmul_rn(x[ 96 + L], x[ 96 + L]);
        const float m7 = __fmul_rn(x[112 + L], x[112 + L]);
        s[L] = __fadd_rn(
            __fadd_rn(__fadd_rn(m0, m1), __fadd_rn(m2, m3)),
            __fadd_rn(__fadd_rn(m4, m5), __fadd_rn(m6, m7)));
    }
    float u[8];
    #pragma unroll
    for (int i = 0; i < 8; ++i) u[i] = __fadd_rn(s[i], s[i + 8]);
    float v[4];
    #pragma unroll
    for (int i = 0; i < 4; ++i) v[i] = __fadd_rn(u[i], u[i + 4]);
    return __fadd_rn(__fadd_rn(v[0], v[2]), __fadd_rn(v[1], v[3]));
}

// scan-phase sq (capture key only)
__device__ __forceinline__ float scan_sq(const float* __restrict__ xp) {
    const float4* x4 = (const float4*)xp;
    float a0 = 0.f, a1 = 0.f, a2 = 0.f, a3 = 0.f;
    #pragma unroll
    for (int g = 0; g < 32; ++g) {
        const float4 b = x4[g];
        a0 += b.x * b.x; a1 += b.y * b.y;
        a2 += b.z * b.z; a3 += b.w * b.w;
    }
    return (a0 + a1) + (a2 + a3);
}

__global__ __launch_bounds__(256)
void sq_kernel(const float* __restrict__ X, float* __restrict__ sqws) {
    const int j = blockIdx.x * 256 + threadIdx.x;
    sqws[j] = 0.5f * scan_sq(X + (size_t)j * DIM);   // half-scale scan key
}

__global__ __launch_bounds__(256)
void cvt_kernel(const float* __restrict__ X, unsigned short* __restrict__ Xb) {
    const size_t i = ((size_t)blockIdx.x * 256 + threadIdx.x) * 8;
    const float4 v0 = *(const float4*)(X + i);
    const float4 v1 = *(const float4*)(X + i + 4);
    ushort4 o0, o1;
    o0.x = f2b(v0.x); o0.y = f2b(v0.y); o0.z = f2b(v0.z); o0.w = f2b(v0.w);
    o1.x = f2b(v1.x); o1.y = f2b(v1.y); o1.z = f2b(v1.z); o1.w = f2b(v1.w);
    *(ushort4*)(Xb + i) = o0;
    *(ushort4*)(Xb + i + 4) = o1;
}

// Two-pass selection, 2-tile iterations (4 independent MFMA chains, 8-load
// MLP per iteration) + branchless med3 insert ladder. (256,2)/128-reg
// operating point (only proven spill-free regime).
__global__ __launch_bounds__(THREADS, 2)
void knn_twopass(const float* __restrict__ X, const float* __restrict__ sqws,
                 const unsigned short* __restrict__ Xb, int* __restrict__ out) {
    __shared__ unsigned long long cand[RPB * CST2];   // 41216 B

    const int tid  = threadIdx.x;
    const int w    = tid >> 6;        // wave 0..3
    const int l    = tid & 63;        // lane
    const int lg   = l >> 4;          // lane-group 0..3
    const int l15  = l & 15;
    const int rloc = (w >> 1) * 16 + l15;           // local row 0..31
    const int grow = blockIdx.x * RPB + rloc;       // global query row
    const int colbase = (w & 1) * (NPTS / 2);       // column half
    const int sid = (w & 1) * 4 + lg;               // scanner 0..7

    // ---- B fragments: NEGATED query row (validated R13+) ----
    bf16x8 nb[4];
    {
        const unsigned short* xr = Xb + (size_t)grow * DIM + lg * 8;
        #pragma unroll
        for (int m = 0; m < 4; ++m) {
            union { bf16x8 h; uint4 u; } t;
            t.h = *(const bf16x8*)(xr + m * 32);
            t.u.x ^= 0x80008000u; t.u.y ^= 0x80008000u;
            t.u.z ^= 0x80008000u; t.u.w ^= 0x80008000u;
            nb[m] = t.h;
        }
    }

    // ---- pass A: values-only top-TSEL, 2 tiles/iter, med3 ladder ----
    float bv[TSEL];
    #pragma unroll
    for (int k = 0; k < TSEL; ++k) bv[k] = 3.0e38f;
    {
        const unsigned short* ap = Xb + (size_t)(colbase + l15) * DIM + lg * 8;
        #pragma unroll 1
        for (int t = 0; t < NT; t += 2) {
            const int cb = colbase + t * 16;
            // 8 fragment loads for two tiles (max MLP at iteration head)
            const bf16x8 a0 = *(const bf16x8*)(ap);
            const bf16x8 a1 = *(const bf16x8*)(ap + 32);
            const bf16x8 a2 = *(const bf16x8*)(ap + 64);
            const bf16x8 a3 = *(const bf16x8*)(ap + 96);
            const bf16x8 b0 = *(const bf16x8*)(ap + 16 * DIM);
            const bf16x8 b1 = *(const bf16x8*)(ap + 16 * DIM + 32);
            const bf16x8 b2 = *(const bf16x8*)(ap + 16 * DIM + 64);
            const bf16x8 b3 = *(const bf16x8*)(ap + 16 * DIM + 96);
            ap += 32 * DIM;
            // 4 independent 2-deep MFMA chains
            f32x4 aA1 = *(const f32x4*)&sqws[cb + lg * 4];
            f32x4 aA2 = {0.f, 0.f, 0.f, 0.f};
            f32x4 aB1 = *(const f32x4*)&sqws[cb + 16 + lg * 4];
            f32x4 aB2 = {0.f, 0.f, 0.f, 0.f};
            aA1 = __builtin_amdgcn_mfma_f32_16x16x32_bf16(a0, nb[0], aA1, 0, 0, 0);
            aA2 = __builtin_amdgcn_mfma_f32_16x16x32_bf16(a2, nb[2], aA2, 0, 0, 0);
            aB1 = __builtin_amdgcn_mfma_f32_16x16x32_bf16(b0, nb[0], aB1, 0, 0, 0);
            aB2 = __builtin_amdgcn_mfma_f32_16x16x32_bf16(b2, nb[2], aB2, 0, 0, 0);
            aA1 = __builtin_amdgcn_mfma_f32_16x16x32_bf16(a1, nb[1], aA1, 0, 0, 0);
            aA2 = __builtin_amdgcn_mfma_f32_16x16x32_bf16(a3, nb[3], aA2, 0, 0, 0);
            aB1 = __builtin_amdgcn_mfma_f32_16x16x32_bf16(b1, nb[1], aB1, 0, 0, 0);
            aB2 = __builtin_amdgcn_mfma_f32_16x16x32_bf16(b3, nb[3], aB2, 0, 0, 0);
            // branchless med3 inserts (8 values)
            #pragma unroll
            for (int r = 0; r < 4; ++r) {
                const float vA = aA1[r] + aA2[r];
                MED3_LADDER(bv, vA);
            }
            #pragma unroll
            for (int r = 0; r < 4; ++r) {
                const float vB = aB1[r] + aB2[r];
                MED3_LADDER(bv, vB);
            }
        }
    }
    const float T = bv[TSEL - 1];   // exact 18th-smallest of this stream

    // ---- init own slots, pass B: collect indices (bit-identical accs) ----
    #pragma unroll
    for (int c = 0; c < CBUF; ++c)
        cand[rloc * CST2 + sid * CBUF + c] = 0xFFFFFFFFFFFFFFFFULL;
    {
        int cnt = 0;
        const unsigned short* ap = Xb + (size_t)(colbase + l15) * DIM + lg * 8;
        #pragma unroll 1
        for (int t = 0; t < NT; t += 2) {
            const int cb = colbase + t * 16;
            const bf16x8 a0 = *(const bf16x8*)(ap);
            const bf16x8 a1 = *(const bf16x8*)(ap + 32);
            const bf16x8 a2 = *(const bf16x8*)(ap + 64);
            const bf16x8 a3 = *(const bf16x8*)(ap + 96);
            const bf16x8 b0 = *(const bf16x8*)(ap + 16 * DIM);
            const bf16x8 b1 = *(const bf16x8*)(ap + 16 * DIM + 32);
            const bf16x8 b2 = *(const bf16x8*)(ap + 16 * DIM + 64);
            const bf16x8 b3 = *(const bf16x8*)(ap + 16 * DIM + 96);
            ap += 32 * DIM;
            f32x4 aA1 = *(const f32x4*)&sqws[cb + lg * 4];
            f32x4 aA2 = {0.f, 0.f, 0.f, 0.f};
            f32x4 aB1 = *(const f32x4*)&sqws[cb + 16 + lg * 4];
            f32x4 aB2 = {0.f, 0.f, 0.f, 0.f};
            aA1 = __builtin_amdgcn_mfma_f32_16x16x32_bf16(a0, nb[0], aA1, 0, 0, 0);
            aA2 = __builtin_amdgcn_mfma_f32_16x16x32_bf16(a2, nb[2], aA2, 0, 0, 0);
            aB1 = __builtin_amdgcn_mfma_f32_16x16x32_bf16(b0, nb[0], aB1, 0, 0, 0);
            aB2 = __builtin_amdgcn_mfma_f32_16x16x32_bf16(b2, nb[2], aB2, 0, 0, 0);
            aA1 = __builtin_amdgcn_mfma_f32_16x16x32_bf16(a1, nb[1], aA1, 0, 0, 0);
            aA2 = __builtin_amdgcn_mfma_f32_16x16x32_bf16(a3, nb[3], aA2, 0, 0, 0);
            aB1 = __builtin_amdgcn_mfma_f32_16x16x32_bf16(b1, nb[1], aB1, 0, 0, 0);
            aB2 = __builtin_amdgcn_mfma_f32_16x16x32_bf16(b3, nb[3], aB2, 0, 0, 0);
            #pragma unroll
            for (int r = 0; r < 4; ++r) {
                const float vA = aA1[r] + aA2[r];     // same ops as pass A
                if (vA <= T && cnt < CBUF) {
                    cand[rloc * CST2 + sid * CBUF + cnt] =
                        (unsigned long long)(unsigned int)(cb + lg * 4 + r);
                    ++cnt;
                }
            }
            #pragma unroll
            for (int r = 0; r < 4; ++r) {
                const float vB = aB1[r] + aB2[r];
                if (vB <= T && cnt < CBUF) {
                    cand[rloc * CST2 + sid * CBUF + cnt] =
                        (unsigned long long)(unsigned int)(cb + 16 + lg * 4 + r);
                    ++cnt;
                }
            }
        }
    }

    // ---- rescore in place: bit-replica np f32 pipeline (validated R9) ----
    float4 xi4[32];
    {
        const float4* xr = (const float4*)(X + (size_t)grow * DIM);
        #pragma unroll
        for (int g = 0; g < 32; ++g) xi4[g] = xr[g];
    }
    const float sqi32 = np_sq_avx512(X + (size_t)grow * DIM);

    #pragma unroll 1
    for (int k = 0; k < CBUF; ++k) {
        const int slot = rloc * CST2 + sid * CBUF + k;
        const unsigned long long j64 = cand[slot];
        if (j64 == 0xFFFFFFFFFFFFFFFFULL) continue;   // empty slot
        const int j = (int)j64;
        if (j == grow) {
            cand[slot] = 0xFFFFFFFFFFFFFFFFULL;        // self: excluded
        } else {
            const float* xjp = X + (size_t)j * DIM;
            const float4* xj = (const float4*)xjp;
            const float sqj32 = np_sq_avx512(xjp);
            float cacc = 0.f;
            #pragma unroll
            for (int g = 0; g < 32; ++g) {
                const float4 a = xi4[g], b = xj[g];
                cacc = __fmaf_rn(a.x, b.x, cacc);
                cacc = __fmaf_rn(a.y, b.y, cacc);
                cacc = __fmaf_rn(a.z, b.z, cacc);
                cacc = __fmaf_rn(a.w, b.w, cacc);
            }
            float d2c = __fsub_rn(__fadd_rn(sqi32, sqj32),
                                  __fmul_rn(2.0f, cacc));
            if (d2c < 0.0f) d2c = 0.0f;
            const float dist32 = sqrtf(d2c);           // f32 sqrt, correct rnd
            cand[slot] = ((unsigned long long)__float_as_uint(dist32) << 32)
                         | (unsigned int)j;
        }
    }
    __syncthreads();

    // ---- per-row top-16 over 160 slots (serial, R20-validated) ----
    if (tid < RPB) {
        const int base = tid * CST2;
        const int i = blockIdx.x * RPB + tid;
        for (int m = 0; m < KSEL; ++m) {
            unsigned long long best = 0xFFFFFFFFFFFFFFFFULL; int bc = 0;
            for (int c2 = 0; c2 < NSC * CBUF; ++c2) {
                const unsigned long long v = cand[base + c2];
                if (v < best) { best = v; bc = c2; }
            }
            out[(size_t)i * KSEL + m] = (int)(best & 0xFFFFFFFFULL);
            cand[base + bc] = 0xFFFFFFFFFFFFFFFFULL;  // remove picked
        }
    }
}

// ---- fallback monolith (R14 verbatim, proven; used only without ws) ----
__global__ __launch_bounds__(THREADS, 2)
void knn_mono(const float* __restrict__ X, int* __restrict__ out) {
    __shared__ __align__(16) char smem[NPTS * 4];
    float* sqh = (float*)smem;
    unsigned long long* keys = (unsigned long long*)smem;
    const int tid = threadIdx.x;
    const int w = tid >> 6, l = tid & 63, lg = l >> 4, l15 = l & 15;
    const int rloc = (w >> 1) * 16 + l15;
    const int grow = blockIdx.x * RPB + rloc;
    const int colbase = (w & 1) * (NPTS / 2);
    const int s = (w & 1) * 4 + lg;
    #pragma unroll 1
    for (int q = 0; q < NPTS / THREADS; ++q) {
        const int j = tid + THREADS * q;
        sqh[j] = 0.5f * scan_sq(X + (size_t)j * DIM);
    }
    __syncthreads();
    bf16x8 nb[4];
    {
        const float* xr = X + (size_t)grow * DIM + lg * 8;
        #pragma unroll
        for (int m = 0; m < 4; ++m) {
            bf16x8 h;
            #pragma unroll
            for (int e = 0; e < 8; ++e) h[e] = (short)f2b(-xr[m * 32 + e]);
            nb[m] = h;
        }
    }
    float bv[TSEL]; int bi[TSEL];
    #pragma unroll
    for (int k = 0; k < TSEL; ++k) { bv[k] = 3.0e38f; bi[k] = 0; }
    const float* apf = X + (size_t)(colbase + l15) * DIM + lg * 8;
    #pragma unroll 1
    for (int t = 0; t < NT; ++t) {
        const int cb = colbase + t * 16;
        bf16x8 a0, a1, a2, a3;
        #pragma unroll
        for (int e = 0; e < 8; ++e) {
            a0[e] = (short)f2b(apf[e]);
            a1[e] = (short)f2b(apf[32 + e]);
            a2[e] = (short)f2b(apf[64 + e]);
            a3[e] = (short)f2b(apf[96 + e]);
        }
        apf += 16 * DIM;
        f32x4 acc = *(const f32x4*)&sqh[cb + lg * 4];
        acc = __builtin_amdgcn_mfma_f32_16x16x32_bf16(a0, nb[0], acc, 0, 0, 0);
        acc = __builtin_amdgcn_mfma_f32_16x16x32_bf16(a1, nb[1], acc, 0, 0, 0);
        acc = __builtin_amdgcn_mfma_f32_16x16x32_bf16(a2, nb[2], acc, 0, 0, 0);
        acc = __builtin_amdgcn_mfma_f32_16x16x32_bf16(a3, nb[3], acc, 0, 0, 0);
        #pragma unroll
        for (int r = 0; r < 4; ++r) {
            const float val = acc[r];
            if (val < bv[TSEL - 1]) {
                const int jg = cb + lg * 4 + r;
                #pragma unroll
                for (int k = TSEL - 1; k >= 1; --k) {
                    const bool m1 = val < bv[k - 1];
                    const bool m2 = val < bv[k];
                    bv[k] = m1 ? bv[k - 1] : (m2 ? val : bv[k]);
                    bi[k] = m1 ? bi[k - 1] : (m2 ? jg  : bi[k]);
                }
                if (val < bv[0]) { bv[0] = val; bi[0] = jg; }
            }
        }
    }
    __syncthreads();
    float4 xi4[32];
    {
        const float4* xr = (const float4*)(X + (size_t)grow * DIM);
        #pragma unroll
        for (int g = 0; g < 32; ++g) xi4[g] = xr[g];
    }
    const float sqi32 = np_sq_avx512(X + (size_t)grow * DIM);
    #pragma unroll
    for (int k = 0; k < TSEL; ++k) {
        const int j = bi[k];
        unsigned long long key;
        if (j == grow) {
            key = 0xFFFFFFFFFFFFFFFFULL;
        } else {
            const float* xjp = X + (size_t)j * DIM;
            const float4* xj = (const float4*)xjp;
            const float sqj32 = np_sq_avx512(xjp);
            float cacc = 0.f;
            #pragma unroll
            for (int g = 0; g < 32; ++g) {
                const float4 a = xi4[g], b = xj[g];
                cacc = __fmaf_rn(a.x, b.x, cacc);
                cacc = __fmaf_rn(a.y, b.y, cacc);
                cacc = __fmaf_rn(a.z, b.z, cacc);
                cacc = __fmaf_rn(a.w, b.w, cacc);
            }
            float d2c = __fsub_rn(__fadd_rn(sqi32, sqj32),
                                  __fmul_rn(2.0f, cacc));
            if (d2c < 0.0f) d2c = 0.0f;
            const float dist32 = sqrtf(d2c);
            key = ((unsigned long long)__float_as_uint(dist32) << 32)
                  | (unsigned int)j;
        }
        keys[rloc * CSTRIDE + s * TSEL + k] = key;
    }
    __syncthreads();
    if (tid < RPB) {
        const int base = tid * CSTRIDE;
        const int i = blockIdx.x * RPB + tid;
        for (int m = 0; m < KSEL; ++m) {
            unsigned long long best = 0xFFFFFFFFFFFFFFFFULL; int bc = 0;
            for (int c2 = 0; c2 < NC; ++c2) {
                const unsigned long long v = keys[base + c2];
                if (v < best) { best = v; bc = c2; }
            }
            out[(size_t)i * KSEL + m] = (int)(best & 0xFFFFFFFFULL);
            keys[base + bc] = 0xFFFFFFFFFFFFFFFFULL;
        }
    }
}

extern "C" void kernel_launch(void* const* d_in, const int* in_sizes, int n_in,
                              void* d_out, int out_size, void* d_ws, size_t ws_size,
                              hipStream_t stream) {
    (void)in_sizes; (void)n_in; (void)out_size;
    const float* X = (const float*)d_in[0];
    int* out = (int*)d_out;
    const size_t WS_NEED = (size_t)NPTS * 4 + (size_t)NPTS * DIM * 2;  // 4.26MB
    if (ws_size >= WS_NEED) {   // proven available R13-R22
        float* sqws = (float*)d_ws;
        unsigned short* Xb = (unsigned short*)((char*)d_ws + (size_t)NPTS * 4);
        sq_kernel<<<dim3(NPTS / 256), dim3(256), 0, stream>>>(X, sqws);
        cvt_kernel<<<dim3(NPTS * DIM / 8 / 256), dim3(256), 0, stream>>>(X, Xb);
        knn_twopass<<<dim3(NPTS / RPB), dim3(THREADS), 0, stream>>>(X, sqws, Xb, out);
    } else {
        knn_mono<<<dim3(NPTS / RPB), dim3(THREADS), 0, stream>>>(X, out);
    }
}